// Round 18
// baseline (487.213 us; speedup 1.0000x reference)
//
#include <hip/hip_runtime.h>
#include <stdint.h>

#define GN  8192
#define GIC 512
#define GOC 256

// GCC-style vectors for inline-asm register tuples (4 VGPRs each).
typedef int   vint4   __attribute__((__vector_size__(16)));
typedef float vfloat4 __attribute__((__vector_size__(16)));

// ---- manual bf16 (no hip_bf16.h) ----
__device__ __forceinline__ float bf2f(uint16_t u) {
  union { uint32_t i; float f; } v; v.i = ((uint32_t)u) << 16; return v.f;
}
__device__ __forceinline__ uint16_t f2bf(float f) {
  union { uint32_t i; float f; } v; v.f = f;
  uint32_t lsb = (v.i >> 16) & 1u;
  v.i += 0x7fffu + lsb;              // round-to-nearest-even
  return (uint16_t)(v.i >> 16);
}
__device__ __forceinline__ float lrelu(float x) { return x > 0.f ? x : 0.5f * x; }
__device__ __forceinline__ float ldin(const void* p, size_t idx, int isbf) {
  return isbf ? bf2f(((const uint16_t*)p)[idx]) : ((const float*)p)[idx];
}

// ---- sentinel: pattern 0x40E0 reads as ~7.0 under both bf16 and fp32 views ----
__global__ __launch_bounds__(256) void k_fill(uint16_t* out, int n) {
  int i = blockIdx.x * 256 + threadIdx.x;
  if (i < n) out[i] = 0x40E0u;
}

// ---- dtype probe: bf16-decode 256 samples of W; all small means bf16 inputs ----
__global__ void k_detect(const void* W, int* flag) {
  __shared__ float mx[64];
  int t = threadIdx.x;
  const uint16_t* p = (const uint16_t*)W;
  float m = 0.f;
  for (int k = 0; k < 4; ++k) {
    float v = fabsf(bf2f(p[t * 4 + k]));
    if (!(v <= 1.0f)) v = 1e30f;
    m = fmaxf(m, v);
  }
  mx[t] = m;
  __syncthreads();
  if (t == 0) {
    float mm = 0.f;
    for (int i = 0; i < 64; ++i) mm = fmaxf(mm, mx[i]);
    flag[0] = (mm < 0.5f) ? 1 : 0;   // 1 = bf16
  }
}

// ---- K1: Wh = h @ W (fp32 accum) -> bf16 WhF in B-fragment layout:
// WhF[((k>>3)*GOC + n)*8 + (k&7)], k = node row (blockIdx covers 8 rows).
// Epilogue also emits Wh1 = Wh@a[:256], Wh2 = Wh@a[256:] from the fp32 accs
// (cross-column LDS tree, reusing hs).
__global__ __launch_bounds__(256) void k_wh(const void* __restrict__ h,
                                            const void* __restrict__ W,
                                            const void* __restrict__ a,
                                            uint16_t* __restrict__ WhF,
                                            float* __restrict__ Wh1,
                                            float* __restrict__ Wh2,
                                            const int* __restrict__ flag) {
  const int isbf = flag[0];
  __shared__ float hs[8][GIC];       // 16 KB; reused by the a-dot reduction
  const int t = threadIdx.x, i0 = blockIdx.x * 8;
  float acc[8] = {0.f, 0.f, 0.f, 0.f, 0.f, 0.f, 0.f, 0.f};
  const int c = t;
  if (isbf) {
    const uint16_t* hp = (const uint16_t*)h;
    const uint16_t* Wp = (const uint16_t*)W;
    for (int x = t; x < 512; x += 256) {          // 8 rows x 64 chunks of 8 bf16
      int r = x >> 6, cc = (x & 63) * 8;
      int4 raw = *(const int4*)&hp[(size_t)(i0 + r) * GIC + cc];
      uint32_t u0 = (uint32_t)raw.x;
      uint32_t u1 = (uint32_t)raw.y;
      uint32_t u2 = (uint32_t)raw.z;
      uint32_t u3 = (uint32_t)raw.w;
      hs[r][cc + 0] = bf2f((uint16_t)(u0 & 0xffffu));
      hs[r][cc + 1] = bf2f((uint16_t)(u0 >> 16));
      hs[r][cc + 2] = bf2f((uint16_t)(u1 & 0xffffu));
      hs[r][cc + 3] = bf2f((uint16_t)(u1 >> 16));
      hs[r][cc + 4] = bf2f((uint16_t)(u2 & 0xffffu));
      hs[r][cc + 5] = bf2f((uint16_t)(u2 >> 16));
      hs[r][cc + 6] = bf2f((uint16_t)(u3 & 0xffffu));
      hs[r][cc + 7] = bf2f((uint16_t)(u3 >> 16));
    }
    __syncthreads();
    for (int k = 0; k < GIC; k += 4) {
      float w0 = bf2f(Wp[(size_t)(k + 0) * GOC + c]);
      float w1 = bf2f(Wp[(size_t)(k + 1) * GOC + c]);
      float w2 = bf2f(Wp[(size_t)(k + 2) * GOC + c]);
      float w3 = bf2f(Wp[(size_t)(k + 3) * GOC + c]);
#pragma unroll
      for (int r = 0; r < 8; ++r) {
        float4 hv = *(const float4*)&hs[r][k];
        acc[r] = fmaf(hv.x, w0, acc[r]);
        acc[r] = fmaf(hv.y, w1, acc[r]);
        acc[r] = fmaf(hv.z, w2, acc[r]);
        acc[r] = fmaf(hv.w, w3, acc[r]);
      }
    }
  } else {
    for (int x = t; x < 8 * GIC; x += 256) {
      int r = x >> 9, k = x & (GIC - 1);
      hs[r][k] = ldin(h, (size_t)(i0 + r) * GIC + k, 0);
    }
    __syncthreads();
    for (int k = 0; k < GIC; ++k) {
      float w = ldin(W, (size_t)k * GOC + c, 0);
#pragma unroll
      for (int r = 0; r < 8; ++r) acc[r] = fmaf(hs[r][k], w, acc[r]);
    }
  }
  int4 pk;
  pk.x = (int)((uint32_t)f2bf(acc[0]) | ((uint32_t)f2bf(acc[1]) << 16));
  pk.y = (int)((uint32_t)f2bf(acc[2]) | ((uint32_t)f2bf(acc[3]) << 16));
  pk.z = (int)((uint32_t)f2bf(acc[4]) | ((uint32_t)f2bf(acc[5]) << 16));
  pk.w = (int)((uint32_t)f2bf(acc[6]) | ((uint32_t)f2bf(acc[7]) << 16));
  *(int4*)&WhF[((size_t)blockIdx.x * GOC + c) * 8] = pk;   // 16B aligned

  // a-dot epilogue: s1/s2 live in the hs LDS region
  const float a1c = ldin(a, c, isbf);
  const float a2c = ldin(a, GOC + c, isbf);
  __syncthreads();                    // all hs reads in the k-loop are done
  float* s1 = &hs[0][0];              // 8*256 floats
  float* s2 = &hs[0][0] + 2048;       // next 8*256 floats
#pragma unroll
  for (int r = 0; r < 8; ++r) {
    s1[r * 256 + c] = acc[r] * a1c;
    s2[r * 256 + c] = acc[r] * a2c;
  }
  __syncthreads();
  for (int o = 128; o > 0; o >>= 1) {
    if (c < o) {
#pragma unroll
      for (int r = 0; r < 8; ++r) {
        s1[r * 256 + c] += s1[r * 256 + c + o];
        s2[r * 256 + c] += s2[r * 256 + c + o];
      }
    }
    __syncthreads();
  }
  if (t < 8) {
    Wh1[i0 + t] = s1[t * 256];
    Wh2[i0 + t] = s2[t * 256];
  }
}

// ---- K3: global max of Wh2 (one block) ----
__global__ __launch_bounds__(256) void k_w2max(const float* __restrict__ Wh2,
                                               float* __restrict__ w2m) {
  __shared__ float red[256];
  const int t = threadIdx.x;
  float m = -3e38f;
  for (int x = t; x < GN / 4; x += 256) {
    float4 v = ((const float4*)Wh2)[x];
    m = fmaxf(m, fmaxf(fmaxf(v.x, v.y), fmaxf(v.z, v.w)));
  }
  red[t] = m;
  __syncthreads();
  for (int o = 128; o > 0; o >>= 1) {
    if (t < o) red[t] = fmaxf(red[t], red[t + o]);
    __syncthreads();
  }
  if (t == 0) w2m[0] = red[0];
}

// ---- K4 (template name): partial GAT over a 1024-j chunk, 32 rows/block.
// Fixed-reference softmax makes partials over disjoint j exactly additive.
// grid = 256 rowgroups x 8 chunks = 2048 blocks -> up to 8 blocks/CU.
// Each B-fragment load feeds TWO MFMAs (low rows 0-15, high rows 16-31).
__global__ __launch_bounds__(256) void GraphAttentionLayer_P1_2834678415522_kernel(
    const int* __restrict__ adj, const uint16_t* __restrict__ WhF,
    const float* __restrict__ Wh1, const float* __restrict__ Wh2,
    const float* __restrict__ w2m, float* __restrict__ pO,
    float* __restrict__ pL) {
  __shared__ uint16_t pA[32][72];
  __shared__ float red32[32][8];
  __shared__ float sb1[32];
  __shared__ float sbM[32];
  const int t = threadIdx.x;
  const int rg = blockIdx.x >> 3;
  const int ch = blockIdx.x & 7;
  const int i0 = rg * 32;
  const int jb = ch * 1024;
  if (t < 32) {
    float b = Wh1[i0 + t];
    sb1[t] = b;
    sbM[t] = lrelu(b + w2m[0]);
  }
  __syncthreads();

  const int ar = t >> 3;              // phase-A row 0..31
  const int a8 = (t & 7) * 8;         // 8 j per thread
  const float vb = sb1[ar];
  const float vM = sbM[ar];
  const int lane = t & 63, w = t >> 6;
  const int quad = lane >> 4, n16 = lane & 15;

  vfloat4 aL0 = {0.f, 0.f, 0.f, 0.f};
  vfloat4 aL1 = {0.f, 0.f, 0.f, 0.f};
  vfloat4 aL2 = {0.f, 0.f, 0.f, 0.f};
  vfloat4 aL3 = {0.f, 0.f, 0.f, 0.f};
  vfloat4 aH0 = {0.f, 0.f, 0.f, 0.f};
  vfloat4 aH1 = {0.f, 0.f, 0.f, 0.f};
  vfloat4 aH2 = {0.f, 0.f, 0.f, 0.f};
  vfloat4 aH3 = {0.f, 0.f, 0.f, 0.f};
  float lsum = 0.f;

  const size_t rowbase = (size_t)(i0 + ar) * GN + jb;
  int4   adjv0 = *(const int4*)&adj[rowbase + a8];
  int4   adjv1 = *(const int4*)&adj[rowbase + a8 + 4];
  float4 w2v0  = *(const float4*)&Wh2[jb + a8];
  float4 w2v1  = *(const float4*)&Wh2[jb + a8 + 4];

  for (int jt = 0; jt < 1024; jt += 64) {
    // ---- phase A: p = exp(e - M) for 8 j's ----
    float e0 = adjv0.x > 0 ? lrelu(vb + w2v0.x) : -9e15f;
    float e1 = adjv0.y > 0 ? lrelu(vb + w2v0.y) : -9e15f;
    float e2 = adjv0.z > 0 ? lrelu(vb + w2v0.z) : -9e15f;
    float e3 = adjv0.w > 0 ? lrelu(vb + w2v0.w) : -9e15f;
    float e4 = adjv1.x > 0 ? lrelu(vb + w2v1.x) : -9e15f;
    float e5 = adjv1.y > 0 ? lrelu(vb + w2v1.y) : -9e15f;
    float e6 = adjv1.z > 0 ? lrelu(vb + w2v1.z) : -9e15f;
    float e7 = adjv1.w > 0 ? lrelu(vb + w2v1.w) : -9e15f;
    float p0 = __expf(e0 - vM);
    float p1 = __expf(e1 - vM);
    float p2 = __expf(e2 - vM);
    float p3 = __expf(e3 - vM);
    float p4 = __expf(e4 - vM);
    float p5 = __expf(e5 - vM);
    float p6 = __expf(e6 - vM);
    float p7 = __expf(e7 - vM);
    *(uint32_t*)&pA[ar][a8]     = (uint32_t)f2bf(p0) | ((uint32_t)f2bf(p1) << 16);
    *(uint32_t*)&pA[ar][a8 + 2] = (uint32_t)f2bf(p2) | ((uint32_t)f2bf(p3) << 16);
    *(uint32_t*)&pA[ar][a8 + 4] = (uint32_t)f2bf(p4) | ((uint32_t)f2bf(p5) << 16);
    *(uint32_t*)&pA[ar][a8 + 6] = (uint32_t)f2bf(p6) | ((uint32_t)f2bf(p7) << 16);
    lsum += ((p0 + p1) + (p2 + p3)) + ((p4 + p5) + (p6 + p7));
    if (jt + 64 < 1024) {
      adjv0 = *(const int4*)&adj[rowbase + jt + 64 + a8];
      adjv1 = *(const int4*)&adj[rowbase + jt + 64 + a8 + 4];
      w2v0  = *(const float4*)&Wh2[jb + jt + 64 + a8];
      w2v1  = *(const float4*)&Wh2[jb + jt + 64 + a8 + 4];
    }
    __syncthreads();
    // ---- phase B: 16 MFMAs per wave, 8 B-loads (each reused twice) ----
    vint4 xa0 = *(const vint4*)&pA[n16][quad * 8];
    vint4 xa1 = *(const vint4*)&pA[n16][32 + quad * 8];
    vint4 xb0 = *(const vint4*)&pA[16 + n16][quad * 8];
    vint4 xb1 = *(const vint4*)&pA[16 + n16][32 + quad * 8];
    const int kb0 = ((jb + jt) >> 3) + quad;
    const uint16_t* bp0 = &WhF[((size_t)kb0 * GOC + w * 64 + n16) * 8];
    const uint16_t* bp1 = &WhF[((size_t)(kb0 + 4) * GOC + w * 64 + n16) * 8];
#pragma unroll
    for (int ct = 0; ct < 4; ++ct) {
      vint4 b0 = *(const vint4*)(bp0 + (size_t)ct * 16 * 8);
      vint4 b1 = *(const vint4*)(bp1 + (size_t)ct * 16 * 8);
      vfloat4* pl = ct == 0 ? &aL0 : ct == 1 ? &aL1 : ct == 2 ? &aL2 : &aL3;
      vfloat4* ph = ct == 0 ? &aH0 : ct == 1 ? &aH1 : ct == 2 ? &aH2 : &aH3;
      __asm__ volatile("s_nop 1\n\tv_mfma_f32_16x16x32_bf16 %0, %1, %2, %0"
                       : "+v"(*pl) : "v"(xa0), "v"(b0));
      __asm__ volatile("s_nop 1\n\tv_mfma_f32_16x16x32_bf16 %0, %1, %2, %0"
                       : "+v"(*pl) : "v"(xa1), "v"(b1));
      __asm__ volatile("s_nop 1\n\tv_mfma_f32_16x16x32_bf16 %0, %1, %2, %0"
                       : "+v"(*ph) : "v"(xb0), "v"(b0));
      __asm__ volatile("s_nop 1\n\tv_mfma_f32_16x16x32_bf16 %0, %1, %2, %0"
                       : "+v"(*ph) : "v"(xb1), "v"(b1));
    }
    __syncthreads();
  }

  red32[ar][t & 7] = lsum;
  __asm__ volatile("s_nop 7\n\ts_nop 7"
                   : "+v"(aL0), "+v"(aL1), "+v"(aL2), "+v"(aL3),
                     "+v"(aH0), "+v"(aH1), "+v"(aH2), "+v"(aH3));
  __syncthreads();
  if (t < 32) {
    float4 v0 = *(const float4*)&red32[t][0];
    float4 v1 = *(const float4*)&red32[t][4];
    pL[(size_t)ch * GN + i0 + t] = ((v0.x + v0.y) + (v0.z + v0.w))
                                 + ((v1.x + v1.y) + (v1.z + v1.w));
  }

  const size_t obase = (size_t)ch * GN + i0;
#pragma unroll
  for (int ct = 0; ct < 4; ++ct) {
    const vfloat4 vL = ct == 0 ? aL0 : ct == 1 ? aL1 : ct == 2 ? aL2 : aL3;
    const vfloat4 vH = ct == 0 ? aH0 : ct == 1 ? aH1 : ct == 2 ? aH2 : aH3;
    const int col = w * 64 + ct * 16 + n16;
    pO[(obase + quad * 4 + 0) * GOC + col] = vL[0];
    pO[(obase + quad * 4 + 1) * GOC + col] = vL[1];
    pO[(obase + quad * 4 + 2) * GOC + col] = vL[2];
    pO[(obase + quad * 4 + 3) * GOC + col] = vL[3];
    pO[(obase + 16 + quad * 4 + 0) * GOC + col] = vH[0];
    pO[(obase + 16 + quad * 4 + 1) * GOC + col] = vH[1];
    pO[(obase + 16 + quad * 4 + 2) * GOC + col] = vH[2];
    pO[(obase + 16 + quad * 4 + 3) * GOC + col] = vH[3];
  }
}

// ---- K5: combine the eight j-chunk partials: out = relu(sum O / sum l) ----
__global__ __launch_bounds__(256) void k_comb(const float* __restrict__ pO,
                                              const float* __restrict__ pL,
                                              void* __restrict__ out,
                                              const int* __restrict__ flag) {
  const int isbf = flag[0];
  size_t gid = ((size_t)blockIdx.x * 256 + threadIdx.x) * 4;
  size_t row = gid >> 8;
  float sx = 0.f, sy = 0.f, sz = 0.f, sw = 0.f, sl = 0.f;
#pragma unroll
  for (int q = 0; q < 8; ++q) {
    float4 v = *(const float4*)&pO[(size_t)q * GN * GOC + gid];
    sx += v.x; sy += v.y; sz += v.z; sw += v.w;
    sl += pL[(size_t)q * GN + row];
  }
  float il = 1.0f / sl;
  float v0 = fmaxf(sx * il, 0.f);
  float v1 = fmaxf(sy * il, 0.f);
  float v2 = fmaxf(sz * il, 0.f);
  float v3 = fmaxf(sw * il, 0.f);
  if (isbf) {
    uint16_t* o = (uint16_t*)out;
    *(uint32_t*)&o[gid]     = (uint32_t)f2bf(v0) | ((uint32_t)f2bf(v1) << 16);
    *(uint32_t*)&o[gid + 2] = (uint32_t)f2bf(v2) | ((uint32_t)f2bf(v3) << 16);
  } else {
    float4 vv;
    vv.x = v0; vv.y = v1; vv.z = v2; vv.w = v3;
    *(float4*)&((float*)out)[gid] = vv;
  }
}

// ---- fallback single-chunk GAT for small ws ----
__global__ __launch_bounds__(256) void k_gat1(
    const int* __restrict__ adj, const uint16_t* __restrict__ WhF,
    const float* __restrict__ Wh1, const float* __restrict__ Wh2,
    const float* __restrict__ w2m, void* __restrict__ out,
    const int* __restrict__ flag) {
  const int isbf = flag[0];
  __shared__ uint16_t pA[16][72];
  __shared__ float red16[16][16];
  __shared__ float sb1[16];
  __shared__ float sbM[16];
  __shared__ float lcS[16];
  const int t = threadIdx.x;
  const int i0 = blockIdx.x * 16;
  if (t < 16) {
    float b = Wh1[i0 + t];
    sb1[t] = b;
    sbM[t] = lrelu(b + w2m[0]);
  }
  __syncthreads();

  const int ar = t >> 4;
  const int c16 = t & 15;
  const int aj = c16 * 4;
  const float vb = sb1[ar];
  const float vM = sbM[ar];
  const int lane = t & 63, w = t >> 6;
  const int quad = lane >> 4, n16 = lane & 15;

  vfloat4 acc0 = {0.f, 0.f, 0.f, 0.f};
  vfloat4 acc1 = {0.f, 0.f, 0.f, 0.f};
  vfloat4 acc2 = {0.f, 0.f, 0.f, 0.f};
  vfloat4 acc3 = {0.f, 0.f, 0.f, 0.f};
  float lsum = 0.f;

  const size_t rowbase = (size_t)(i0 + ar) * GN;
  int4   adjv = *(const int4*)&adj[rowbase + aj];
  float4 w2v  = *(const float4*)&Wh2[aj];

  for (int j0 = 0; j0 < GN; j0 += 64) {
    float e0 = adjv.x > 0 ? lrelu(vb + w2v.x) : -9e15f;
    float e1 = adjv.y > 0 ? lrelu(vb + w2v.y) : -9e15f;
    float e2 = adjv.z > 0 ? lrelu(vb + w2v.z) : -9e15f;
    float e3 = adjv.w > 0 ? lrelu(vb + w2v.w) : -9e15f;
    float p0 = __expf(e0 - vM);
    float p1 = __expf(e1 - vM);
    float p2 = __expf(e2 - vM);
    float p3 = __expf(e3 - vM);
    *(uint32_t*)&pA[ar][aj]     = (uint32_t)f2bf(p0) | ((uint32_t)f2bf(p1) << 16);
    *(uint32_t*)&pA[ar][aj + 2] = (uint32_t)f2bf(p2) | ((uint32_t)f2bf(p3) << 16);
    lsum += (p0 + p1) + (p2 + p3);
    if (j0 + 64 < GN) {
      adjv = *(const int4*)&adj[rowbase + j0 + 64 + aj];
      w2v  = *(const float4*)&Wh2[j0 + 64 + aj];
    }
    __syncthreads();
    vint4 a0 = *(const vint4*)&pA[n16][quad * 8];
    vint4 a1 = *(const vint4*)&pA[n16][32 + quad * 8];
    const int kb0 = (j0 >> 3) + quad;
    const uint16_t* bp0 = &WhF[((size_t)kb0 * GOC + w * 64 + n16) * 8];
    const uint16_t* bp1 = &WhF[((size_t)(kb0 + 4) * GOC + w * 64 + n16) * 8];
#pragma unroll
    for (int ct = 0; ct < 4; ++ct) {
      vint4 b0 = *(const vint4*)(bp0 + (size_t)ct * 16 * 8);
      vint4 b1 = *(const vint4*)(bp1 + (size_t)ct * 16 * 8);
      vfloat4* accp = ct == 0 ? &acc0 : ct == 1 ? &acc1 : ct == 2 ? &acc2 : &acc3;
      __asm__ volatile("s_nop 1\n\tv_mfma_f32_16x16x32_bf16 %0, %1, %2, %0"
                       : "+v"(*accp) : "v"(a0), "v"(b0));
      __asm__ volatile("s_nop 1\n\tv_mfma_f32_16x16x32_bf16 %0, %1, %2, %0"
                       : "+v"(*accp) : "v"(a1), "v"(b1));
    }
    __syncthreads();
  }

  red16[ar][c16] = lsum;
  __asm__ volatile("s_nop 7\n\ts_nop 7"
                   : "+v"(acc0), "+v"(acc1), "+v"(acc2), "+v"(acc3));
  __syncthreads();
  if (t < 16) {
    float s = 0.f;
    for (int i = 0; i < 16; ++i) s += red16[t][i];
    lcS[t] = 1.0f / s;
  }
  __syncthreads();

  const float il0 = lcS[quad * 4 + 0];
  const float il1 = lcS[quad * 4 + 1];
  const float il2 = lcS[quad * 4 + 2];
  const float il3 = lcS[quad * 4 + 3];
#pragma unroll
  for (int ct = 0; ct < 4; ++ct) {
    const vfloat4 av = ct == 0 ? acc0 : ct == 1 ? acc1 : ct == 2 ? acc2 : acc3;
    const int col = w * 64 + ct * 16 + n16;
    float v0 = fmaxf(av[0] * il0, 0.f);
    float v1 = fmaxf(av[1] * il1, 0.f);
    float v2 = fmaxf(av[2] * il2, 0.f);
    float v3 = fmaxf(av[3] * il3, 0.f);
    if (isbf) {
      uint16_t* o = (uint16_t*)out;
      o[(size_t)(i0 + quad * 4 + 0) * GOC + col] = f2bf(v0);
      o[(size_t)(i0 + quad * 4 + 1) * GOC + col] = f2bf(v1);
      o[(size_t)(i0 + quad * 4 + 2) * GOC + col] = f2bf(v2);
      o[(size_t)(i0 + quad * 4 + 3) * GOC + col] = f2bf(v3);
    } else {
      float* o = (float*)out;
      o[(size_t)(i0 + quad * 4 + 0) * GOC + col] = v0;
      o[(size_t)(i0 + quad * 4 + 1) * GOC + col] = v1;
      o[(size_t)(i0 + quad * 4 + 2) * GOC + col] = v2;
      o[(size_t)(i0 + quad * 4 + 3) * GOC + col] = v3;
    }
  }
}

extern "C" void kernel_launch(void* const* d_in, const int* in_sizes, int n_in,
                              void* d_out, int out_size, void* d_ws, size_t ws_size,
                              hipStream_t stream) {
  // ws: WhF u16[GN*GOC] (4MB) | Wh1[GN] | Wh2[GN] | pO f32[8*GN*GOC] (64MB)
  //     | pL f32[8*GN] | flag | w2m
  uint16_t* WhF = (uint16_t*)d_ws;
  float* Wh1  = (float*)(WhF + (size_t)GN * GOC);
  float* Wh2  = Wh1 + GN;
  float* pO   = Wh2 + GN;
  float* pL   = pO + (size_t)8 * GN * GOC;
  int*   flag = (int*)(pL + 8 * GN);
  float* w2m  = (float*)(flag + 1);
  size_t need = (size_t)((char*)(w2m + 1) - (char*)d_ws);
  const int use_split = (ws_size >= need) ? 1 : 0;   // ws_size constant: same work every call
  if (!use_split) {                    // tight fallback layout without pO/pL
    flag = (int*)(Wh2 + GN);
    w2m  = (float*)(flag + 1);
  }

  const void* h = d_in[0]; const void* adj = d_in[1];
  const void* W = d_in[2]; const void* a = d_in[3];
  for (int i = 0; i < n_in; ++i) {
    long long s = in_sizes[i];
    if      (s == (long long)GN * GIC)  h   = d_in[i];
    else if (s == (long long)GN * GN)   adj = d_in[i];
    else if (s == (long long)GIC * GOC) W   = d_in[i];
    else if (s == 2LL * GOC)            a   = d_in[i];
  }

  const int n_out = GN * GOC;
  k_fill<<<(n_out + 255) / 256, 256, 0, stream>>>((uint16_t*)d_out, n_out);  // sentinel
  k_detect<<<1, 64, 0, stream>>>(W, flag);
  k_wh <<<GN / 8, 256, 0, stream>>>(h, W, a, WhF, Wh1, Wh2, flag);
  k_w2max<<<1, 256, 0, stream>>>(Wh2, w2m);
  if (use_split) {
    GraphAttentionLayer_P1_2834678415522_kernel<<<(GN / 32) * 8, 256, 0, stream>>>(
        (const int*)adj, WhF, Wh1, Wh2, w2m, pO, pL);
    k_comb<<<(GN * GOC) / 1024, 256, 0, stream>>>(pO, pL, d_out, flag);
  } else {
    k_gat1<<<GN / 16, 256, 0, stream>>>((const int*)adj, WhF, Wh1, Wh2, w2m,
                                        d_out, flag);
  }
}

// Round 20
// 484.657 us; speedup vs baseline: 1.0053x; 1.0053x over previous
//
#include <hip/hip_runtime.h>
#include <stdint.h>

#define GN  8192
#define GIC 512
#define GOC 256

// GCC-style vectors for inline-asm register tuples (4 VGPRs each).
typedef int   vint4   __attribute__((__vector_size__(16)));
typedef float vfloat4 __attribute__((__vector_size__(16)));

// ---- manual bf16 (no hip_bf16.h) ----
__device__ __forceinline__ float bf2f(uint16_t u) {
  union { uint32_t i; float f; } v; v.i = ((uint32_t)u) << 16; return v.f;
}
__device__ __forceinline__ uint16_t f2bf(float f) {
  union { uint32_t i; float f; } v; v.f = f;
  uint32_t lsb = (v.i >> 16) & 1u;
  v.i += 0x7fffu + lsb;              // round-to-nearest-even
  return (uint16_t)(v.i >> 16);
}
__device__ __forceinline__ float lrelu(float x) { return x > 0.f ? x : 0.5f * x; }
__device__ __forceinline__ float ldin(const void* p, size_t idx, int isbf) {
  return isbf ? bf2f(((const uint16_t*)p)[idx]) : ((const float*)p)[idx];
}

// ---- sentinel: pattern 0x40E0 reads as ~7.0 under both bf16 and fp32 views ----
__global__ __launch_bounds__(256) void k_fill(uint16_t* out, int n) {
  int i = blockIdx.x * 256 + threadIdx.x;
  if (i < n) out[i] = 0x40E0u;
}

// ---- dtype probe: bf16-decode 256 samples of W; all small means bf16 inputs ----
__global__ void k_detect(const void* W, int* flag) {
  __shared__ float mx[64];
  int t = threadIdx.x;
  const uint16_t* p = (const uint16_t*)W;
  float m = 0.f;
  for (int k = 0; k < 4; ++k) {
    float v = fabsf(bf2f(p[t * 4 + k]));
    if (!(v <= 1.0f)) v = 1e30f;
    m = fmaxf(m, v);
  }
  mx[t] = m;
  __syncthreads();
  if (t == 0) {
    float mm = 0.f;
    for (int i = 0; i < 64; ++i) mm = fmaxf(mm, mx[i]);
    flag[0] = (mm < 0.5f) ? 1 : 0;   // 1 = bf16
  }
}

// ---- K1: Wh = h @ W (fp32 accum) -> bf16 WhF in B-fragment layout:
// WhF[((k>>3)*GOC + n)*8 + (k&7)], k = node row (blockIdx covers 8 rows).
// Epilogue also emits Wh1 = Wh@a[:256], Wh2 = Wh@a[256:] from the fp32 accs
// (cross-column LDS tree, reusing hs) -- replaces the old k_wha kernel.
__global__ __launch_bounds__(256) void k_wh(const void* __restrict__ h,
                                            const void* __restrict__ W,
                                            const void* __restrict__ a,
                                            uint16_t* __restrict__ WhF,
                                            float* __restrict__ Wh1,
                                            float* __restrict__ Wh2,
                                            const int* __restrict__ flag) {
  const int isbf = flag[0];
  __shared__ float hs[8][GIC];       // 16 KB; reused by the a-dot reduction
  const int t = threadIdx.x, i0 = blockIdx.x * 8;
  float acc[8] = {0.f, 0.f, 0.f, 0.f, 0.f, 0.f, 0.f, 0.f};
  const int c = t;
  if (isbf) {
    const uint16_t* hp = (const uint16_t*)h;
    const uint16_t* Wp = (const uint16_t*)W;
    for (int x = t; x < 512; x += 256) {          // 8 rows x 64 chunks of 8 bf16
      int r = x >> 6, cc = (x & 63) * 8;
      int4 raw = *(const int4*)&hp[(size_t)(i0 + r) * GIC + cc];
      uint32_t u0 = (uint32_t)raw.x;
      uint32_t u1 = (uint32_t)raw.y;
      uint32_t u2 = (uint32_t)raw.z;
      uint32_t u3 = (uint32_t)raw.w;
      hs[r][cc + 0] = bf2f((uint16_t)(u0 & 0xffffu));
      hs[r][cc + 1] = bf2f((uint16_t)(u0 >> 16));
      hs[r][cc + 2] = bf2f((uint16_t)(u1 & 0xffffu));
      hs[r][cc + 3] = bf2f((uint16_t)(u1 >> 16));
      hs[r][cc + 4] = bf2f((uint16_t)(u2 & 0xffffu));
      hs[r][cc + 5] = bf2f((uint16_t)(u2 >> 16));
      hs[r][cc + 6] = bf2f((uint16_t)(u3 & 0xffffu));
      hs[r][cc + 7] = bf2f((uint16_t)(u3 >> 16));
    }
    __syncthreads();
    for (int k = 0; k < GIC; k += 4) {
      float w0 = bf2f(Wp[(size_t)(k + 0) * GOC + c]);
      float w1 = bf2f(Wp[(size_t)(k + 1) * GOC + c]);
      float w2 = bf2f(Wp[(size_t)(k + 2) * GOC + c]);
      float w3 = bf2f(Wp[(size_t)(k + 3) * GOC + c]);
#pragma unroll
      for (int r = 0; r < 8; ++r) {
        float4 hv = *(const float4*)&hs[r][k];
        acc[r] = fmaf(hv.x, w0, acc[r]);
        acc[r] = fmaf(hv.y, w1, acc[r]);
        acc[r] = fmaf(hv.z, w2, acc[r]);
        acc[r] = fmaf(hv.w, w3, acc[r]);
      }
    }
  } else {
    for (int x = t; x < 8 * GIC; x += 256) {
      int r = x >> 9, k = x & (GIC - 1);
      hs[r][k] = ldin(h, (size_t)(i0 + r) * GIC + k, 0);
    }
    __syncthreads();
    for (int k = 0; k < GIC; ++k) {
      float w = ldin(W, (size_t)k * GOC + c, 0);
#pragma unroll
      for (int r = 0; r < 8; ++r) acc[r] = fmaf(hs[r][k], w, acc[r]);
    }
  }
  int4 pk;
  pk.x = (int)((uint32_t)f2bf(acc[0]) | ((uint32_t)f2bf(acc[1]) << 16));
  pk.y = (int)((uint32_t)f2bf(acc[2]) | ((uint32_t)f2bf(acc[3]) << 16));
  pk.z = (int)((uint32_t)f2bf(acc[4]) | ((uint32_t)f2bf(acc[5]) << 16));
  pk.w = (int)((uint32_t)f2bf(acc[6]) | ((uint32_t)f2bf(acc[7]) << 16));
  *(int4*)&WhF[((size_t)blockIdx.x * GOC + c) * 8] = pk;   // 16B aligned

  // a-dot epilogue: s1/s2 live in the hs LDS region
  const float a1c = ldin(a, c, isbf);
  const float a2c = ldin(a, GOC + c, isbf);
  __syncthreads();                    // all hs reads in the k-loop are done
  float* s1 = &hs[0][0];              // 8*256 floats
  float* s2 = &hs[0][0] + 2048;       // next 8*256 floats
#pragma unroll
  for (int r = 0; r < 8; ++r) {
    s1[r * 256 + c] = acc[r] * a1c;
    s2[r * 256 + c] = acc[r] * a2c;
  }
  __syncthreads();
  for (int o = 128; o > 0; o >>= 1) {
    if (c < o) {
#pragma unroll
      for (int r = 0; r < 8; ++r) {
        s1[r * 256 + c] += s1[r * 256 + c + o];
        s2[r * 256 + c] += s2[r * 256 + c + o];
      }
    }
    __syncthreads();
  }
  if (t < 8) {
    Wh1[i0 + t] = s1[t * 256];
    Wh2[i0 + t] = s2[t * 256];
  }
}

// ---- K3: global max of Wh2 (one block) ----
__global__ __launch_bounds__(256) void k_w2max(const float* __restrict__ Wh2,
                                               float* __restrict__ w2m) {
  __shared__ float red[256];
  const int t = threadIdx.x;
  float m = -3e38f;
  for (int x = t; x < GN / 4; x += 256) {
    float4 v = ((const float4*)Wh2)[x];
    m = fmaxf(m, fmaxf(fmaxf(v.x, v.y), fmaxf(v.z, v.w)));
  }
  red[t] = m;
  __syncthreads();
  for (int o = 128; o > 0; o >>= 1) {
    if (t < o) red[t] = fmaxf(red[t], red[t + o]);
    __syncthreads();
  }
  if (t == 0) w2m[0] = red[0];
}

// ---- K4 (template name): partial GAT over a 2048-j chunk, 32 rows/block.
// Fixed-reference softmax makes partials over disjoint j exactly additive.
// grid = 256 rowgroups x 4 chunks = 1024 blocks -> 4 blocks/CU.
// Each B-fragment load feeds TWO MFMAs (low rows 0-15, high rows 16-31):
// halves L2 WhF traffic and doubles MFMA density vs rows=16.
__global__ __launch_bounds__(256) void GraphAttentionLayer_P1_2834678415522_kernel(
    const int* __restrict__ adj, const uint16_t* __restrict__ WhF,
    const float* __restrict__ Wh1, const float* __restrict__ Wh2,
    const float* __restrict__ w2m, float* __restrict__ pO,
    float* __restrict__ pL) {
  __shared__ uint16_t pA[32][72];
  __shared__ float red32[32][8];
  __shared__ float sb1[32];
  __shared__ float sbM[32];
  const int t = threadIdx.x;
  const int rg = blockIdx.x >> 2;
  const int ch = blockIdx.x & 3;
  const int i0 = rg * 32;
  const int jb = ch * 2048;
  if (t < 32) {
    float b = Wh1[i0 + t];
    sb1[t] = b;
    sbM[t] = lrelu(b + w2m[0]);
  }
  __syncthreads();

  const int ar = t >> 3;              // phase-A row 0..31
  const int a8 = (t & 7) * 8;         // 8 j per thread
  const float vb = sb1[ar];
  const float vM = sbM[ar];
  const int lane = t & 63, w = t >> 6;
  const int quad = lane >> 4, n16 = lane & 15;

  vfloat4 aL0 = {0.f, 0.f, 0.f, 0.f};
  vfloat4 aL1 = {0.f, 0.f, 0.f, 0.f};
  vfloat4 aL2 = {0.f, 0.f, 0.f, 0.f};
  vfloat4 aL3 = {0.f, 0.f, 0.f, 0.f};
  vfloat4 aH0 = {0.f, 0.f, 0.f, 0.f};
  vfloat4 aH1 = {0.f, 0.f, 0.f, 0.f};
  vfloat4 aH2 = {0.f, 0.f, 0.f, 0.f};
  vfloat4 aH3 = {0.f, 0.f, 0.f, 0.f};
  float lsum = 0.f;

  const size_t rowbase = (size_t)(i0 + ar) * GN + jb;
  int4   adjv0 = *(const int4*)&adj[rowbase + a8];
  int4   adjv1 = *(const int4*)&adj[rowbase + a8 + 4];
  float4 w2v0  = *(const float4*)&Wh2[jb + a8];
  float4 w2v1  = *(const float4*)&Wh2[jb + a8 + 4];

  for (int jt = 0; jt < 2048; jt += 64) {
    // ---- phase A: p = exp(e - M) for 8 j's ----
    float e0 = adjv0.x > 0 ? lrelu(vb + w2v0.x) : -9e15f;
    float e1 = adjv0.y > 0 ? lrelu(vb + w2v0.y) : -9e15f;
    float e2 = adjv0.z > 0 ? lrelu(vb + w2v0.z) : -9e15f;
    float e3 = adjv0.w > 0 ? lrelu(vb + w2v0.w) : -9e15f;
    float e4 = adjv1.x > 0 ? lrelu(vb + w2v1.x) : -9e15f;
    float e5 = adjv1.y > 0 ? lrelu(vb + w2v1.y) : -9e15f;
    float e6 = adjv1.z > 0 ? lrelu(vb + w2v1.z) : -9e15f;
    float e7 = adjv1.w > 0 ? lrelu(vb + w2v1.w) : -9e15f;
    float p0 = __expf(e0 - vM);
    float p1 = __expf(e1 - vM);
    float p2 = __expf(e2 - vM);
    float p3 = __expf(e3 - vM);
    float p4 = __expf(e4 - vM);
    float p5 = __expf(e5 - vM);
    float p6 = __expf(e6 - vM);
    float p7 = __expf(e7 - vM);
    *(uint32_t*)&pA[ar][a8]     = (uint32_t)f2bf(p0) | ((uint32_t)f2bf(p1) << 16);
    *(uint32_t*)&pA[ar][a8 + 2] = (uint32_t)f2bf(p2) | ((uint32_t)f2bf(p3) << 16);
    *(uint32_t*)&pA[ar][a8 + 4] = (uint32_t)f2bf(p4) | ((uint32_t)f2bf(p5) << 16);
    *(uint32_t*)&pA[ar][a8 + 6] = (uint32_t)f2bf(p6) | ((uint32_t)f2bf(p7) << 16);
    lsum += ((p0 + p1) + (p2 + p3)) + ((p4 + p5) + (p6 + p7));
    if (jt + 64 < 2048) {
      adjv0 = *(const int4*)&adj[rowbase + jt + 64 + a8];
      adjv1 = *(const int4*)&adj[rowbase + jt + 64 + a8 + 4];
      w2v0  = *(const float4*)&Wh2[jb + jt + 64 + a8];
      w2v1  = *(const float4*)&Wh2[jb + jt + 64 + a8 + 4];
    }
    __syncthreads();
    // ---- phase B: 16 MFMAs per wave, 8 B-loads (each reused twice) ----
    vint4 xa0 = *(const vint4*)&pA[n16][quad * 8];         // low rows, k [0,32)
    vint4 xa1 = *(const vint4*)&pA[n16][32 + quad * 8];    // low rows, k [32,64)
    vint4 xb0 = *(const vint4*)&pA[16 + n16][quad * 8];    // high rows
    vint4 xb1 = *(const vint4*)&pA[16 + n16][32 + quad * 8];
    const int kb0 = ((jb + jt) >> 3) + quad;
    const uint16_t* bp0 = &WhF[((size_t)kb0 * GOC + w * 64 + n16) * 8];
    const uint16_t* bp1 = &WhF[((size_t)(kb0 + 4) * GOC + w * 64 + n16) * 8];
#pragma unroll
    for (int ct = 0; ct < 4; ++ct) {
      vint4 b0 = *(const vint4*)(bp0 + (size_t)ct * 16 * 8);
      vint4 b1 = *(const vint4*)(bp1 + (size_t)ct * 16 * 8);
      vfloat4* pl = ct == 0 ? &aL0 : ct == 1 ? &aL1 : ct == 2 ? &aL2 : &aL3;
      vfloat4* ph = ct == 0 ? &aH0 : ct == 1 ? &aH1 : ct == 2 ? &aH2 : &aH3;
      __asm__ volatile("s_nop 1\n\tv_mfma_f32_16x16x32_bf16 %0, %1, %2, %0"
                       : "+v"(*pl) : "v"(xa0), "v"(b0));
      __asm__ volatile("s_nop 1\n\tv_mfma_f32_16x16x32_bf16 %0, %1, %2, %0"
                       : "+v"(*pl) : "v"(xa1), "v"(b1));
      __asm__ volatile("s_nop 1\n\tv_mfma_f32_16x16x32_bf16 %0, %1, %2, %0"
                       : "+v"(*ph) : "v"(xb0), "v"(b0));
      __asm__ volatile("s_nop 1\n\tv_mfma_f32_16x16x32_bf16 %0, %1, %2, %0"
                       : "+v"(*ph) : "v"(xb1), "v"(b1));
    }
    __syncthreads();
  }

  red32[ar][t & 7] = lsum;
  __asm__ volatile("s_nop 7\n\ts_nop 7"
                   : "+v"(aL0), "+v"(aL1), "+v"(aL2), "+v"(aL3),
                     "+v"(aH0), "+v"(aH1), "+v"(aH2), "+v"(aH3));
  __syncthreads();
  if (t < 32) {
    float4 v0 = *(const float4*)&red32[t][0];
    float4 v1 = *(const float4*)&red32[t][4];
    pL[(size_t)ch * GN + i0 + t] = ((v0.x + v0.y) + (v0.z + v0.w))
                                 + ((v1.x + v1.y) + (v1.z + v1.w));
  }

  const size_t obase = (size_t)ch * GN + i0;
#pragma unroll
  for (int ct = 0; ct < 4; ++ct) {
    const vfloat4 vL = ct == 0 ? aL0 : ct == 1 ? aL1 : ct == 2 ? aL2 : aL3;
    const vfloat4 vH = ct == 0 ? aH0 : ct == 1 ? aH1 : ct == 2 ? aH2 : aH3;
    const int col = w * 64 + ct * 16 + n16;
    pO[(obase + quad * 4 + 0) * GOC + col] = vL[0];
    pO[(obase + quad * 4 + 1) * GOC + col] = vL[1];
    pO[(obase + quad * 4 + 2) * GOC + col] = vL[2];
    pO[(obase + quad * 4 + 3) * GOC + col] = vL[3];
    pO[(obase + 16 + quad * 4 + 0) * GOC + col] = vH[0];
    pO[(obase + 16 + quad * 4 + 1) * GOC + col] = vH[1];
    pO[(obase + 16 + quad * 4 + 2) * GOC + col] = vH[2];
    pO[(obase + 16 + quad * 4 + 3) * GOC + col] = vH[3];
  }
}

// ---- K5: combine the four j-chunk partials: out = relu(sum O / sum l) ----
__global__ __launch_bounds__(256) void k_comb(const float* __restrict__ pO,
                                              const float* __restrict__ pL,
                                              void* __restrict__ out,
                                              const int* __restrict__ flag) {
  const int isbf = flag[0];
  size_t gid = ((size_t)blockIdx.x * 256 + threadIdx.x) * 4;
  size_t row = gid >> 8;
  float4 a0 = *(const float4*)&pO[gid];
  float4 a1 = *(const float4*)&pO[(size_t)GN * GOC + gid];
  float4 a2 = *(const float4*)&pO[(size_t)2 * GN * GOC + gid];
  float4 a3 = *(const float4*)&pO[(size_t)3 * GN * GOC + gid];
  float il = 1.0f / (pL[row] + pL[GN + row] + pL[2 * GN + row] + pL[3 * GN + row]);
  float v0 = fmaxf((a0.x + a1.x + a2.x + a3.x) * il, 0.f);
  float v1 = fmaxf((a0.y + a1.y + a2.y + a3.y) * il, 0.f);
  float v2 = fmaxf((a0.z + a1.z + a2.z + a3.z) * il, 0.f);
  float v3 = fmaxf((a0.w + a1.w + a2.w + a3.w) * il, 0.f);
  if (isbf) {
    uint16_t* o = (uint16_t*)out;
    *(uint32_t*)&o[gid]     = (uint32_t)f2bf(v0) | ((uint32_t)f2bf(v1) << 16);
    *(uint32_t*)&o[gid + 2] = (uint32_t)f2bf(v2) | ((uint32_t)f2bf(v3) << 16);
  } else {
    float4 vv;
    vv.x = v0; vv.y = v1; vv.z = v2; vv.w = v3;
    *(float4*)&((float*)out)[gid] = vv;
  }
}

// ---- fallback single-chunk GAT (R14-proven text) for small ws ----
__global__ __launch_bounds__(256) void k_gat1(
    const int* __restrict__ adj, const uint16_t* __restrict__ WhF,
    const float* __restrict__ Wh1, const float* __restrict__ Wh2,
    const float* __restrict__ w2m, void* __restrict__ out,
    const int* __restrict__ flag) {
  const int isbf = flag[0];
  __shared__ uint16_t pA[16][72];
  __shared__ float red16[16][16];
  __shared__ float sb1[16];
  __shared__ float sbM[16];
  __shared__ float lcS[16];
  const int t = threadIdx.x;
  const int i0 = blockIdx.x * 16;
  if (t < 16) {
    float b = Wh1[i0 + t];
    sb1[t] = b;
    sbM[t] = lrelu(b + w2m[0]);
  }
  __syncthreads();

  const int ar = t >> 4;
  const int c16 = t & 15;
  const int aj = c16 * 4;
  const float vb = sb1[ar];
  const float vM = sbM[ar];
  const int lane = t & 63, w = t >> 6;
  const int quad = lane >> 4, n16 = lane & 15;

  vfloat4 acc0 = {0.f, 0.f, 0.f, 0.f};
  vfloat4 acc1 = {0.f, 0.f, 0.f, 0.f};
  vfloat4 acc2 = {0.f, 0.f, 0.f, 0.f};
  vfloat4 acc3 = {0.f, 0.f, 0.f, 0.f};
  float lsum = 0.f;

  const size_t rowbase = (size_t)(i0 + ar) * GN;
  int4   adjv = *(const int4*)&adj[rowbase + aj];
  float4 w2v  = *(const float4*)&Wh2[aj];

  for (int j0 = 0; j0 < GN; j0 += 64) {
    float e0 = adjv.x > 0 ? lrelu(vb + w2v.x) : -9e15f;
    float e1 = adjv.y > 0 ? lrelu(vb + w2v.y) : -9e15f;
    float e2 = adjv.z > 0 ? lrelu(vb + w2v.z) : -9e15f;
    float e3 = adjv.w > 0 ? lrelu(vb + w2v.w) : -9e15f;
    float p0 = __expf(e0 - vM);
    float p1 = __expf(e1 - vM);
    float p2 = __expf(e2 - vM);
    float p3 = __expf(e3 - vM);
    *(uint32_t*)&pA[ar][aj]     = (uint32_t)f2bf(p0) | ((uint32_t)f2bf(p1) << 16);
    *(uint32_t*)&pA[ar][aj + 2] = (uint32_t)f2bf(p2) | ((uint32_t)f2bf(p3) << 16);
    lsum += (p0 + p1) + (p2 + p3);
    if (j0 + 64 < GN) {
      adjv = *(const int4*)&adj[rowbase + j0 + 64 + aj];
      w2v  = *(const float4*)&Wh2[j0 + 64 + aj];
    }
    __syncthreads();
    vint4 a0 = *(const vint4*)&pA[n16][quad * 8];
    vint4 a1 = *(const vint4*)&pA[n16][32 + quad * 8];
    const int kb0 = (j0 >> 3) + quad;
    const uint16_t* bp0 = &WhF[((size_t)kb0 * GOC + w * 64 + n16) * 8];
    const uint16_t* bp1 = &WhF[((size_t)(kb0 + 4) * GOC + w * 64 + n16) * 8];
#pragma unroll
    for (int ct = 0; ct < 4; ++ct) {
      vint4 b0 = *(const vint4*)(bp0 + (size_t)ct * 16 * 8);
      vint4 b1 = *(const vint4*)(bp1 + (size_t)ct * 16 * 8);
      vfloat4* accp = ct == 0 ? &acc0 : ct == 1 ? &acc1 : ct == 2 ? &acc2 : &acc3;
      __asm__ volatile("s_nop 1\n\tv_mfma_f32_16x16x32_bf16 %0, %1, %2, %0"
                       : "+v"(*accp) : "v"(a0), "v"(b0));
      __asm__ volatile("s_nop 1\n\tv_mfma_f32_16x16x32_bf16 %0, %1, %2, %0"
                       : "+v"(*accp) : "v"(a1), "v"(b1));
    }
    __syncthreads();
  }

  red16[ar][c16] = lsum;
  __asm__ volatile("s_nop 7\n\ts_nop 7"
                   : "+v"(acc0), "+v"(acc1), "+v"(acc2), "+v"(acc3));
  __syncthreads();
  if (t < 16) {
    float s = 0.f;
    for (int i = 0; i < 16; ++i) s += red16[t][i];
    lcS[t] = 1.0f / s;
  }
  __syncthreads();

  const float il0 = lcS[quad * 4 + 0];
  const float il1 = lcS[quad * 4 + 1];
  const float il2 = lcS[quad * 4 + 2];
  const float il3 = lcS[quad * 4 + 3];
#pragma unroll
  for (int ct = 0; ct < 4; ++ct) {
    const vfloat4 av = ct == 0 ? acc0 : ct == 1 ? acc1 : ct == 2 ? acc2 : acc3;
    const int col = w * 64 + ct * 16 + n16;
    float v0 = fmaxf(av[0] * il0, 0.f);
    float v1 = fmaxf(av[1] * il1, 0.f);
    float v2 = fmaxf(av[2] * il2, 0.f);
    float v3 = fmaxf(av[3] * il3, 0.f);
    if (isbf) {
      uint16_t* o = (uint16_t*)out;
      o[(size_t)(i0 + quad * 4 + 0) * GOC + col] = f2bf(v0);
      o[(size_t)(i0 + quad * 4 + 1) * GOC + col] = f2bf(v1);
      o[(size_t)(i0 + quad * 4 + 2) * GOC + col] = f2bf(v2);
      o[(size_t)(i0 + quad * 4 + 3) * GOC + col] = f2bf(v3);
    } else {
      float* o = (float*)out;
      o[(size_t)(i0 + quad * 4 + 0) * GOC + col] = v0;
      o[(size_t)(i0 + quad * 4 + 1) * GOC + col] = v1;
      o[(size_t)(i0 + quad * 4 + 2) * GOC + col] = v2;
      o[(size_t)(i0 + quad * 4 + 3) * GOC + col] = v3;
    }
  }
}

extern "C" void kernel_launch(void* const* d_in, const int* in_sizes, int n_in,
                              void* d_out, int out_size, void* d_ws, size_t ws_size,
                              hipStream_t stream) {
  // ws: WhF u16[GN*GOC] (4MB) | Wh1[GN] | Wh2[GN] | pO f32[4*GN*GOC] (32MB)
  //     | pL f32[4*GN] | flag | w2m
  uint16_t* WhF = (uint16_t*)d_ws;
  float* Wh1  = (float*)(WhF + (size_t)GN * GOC);
  float* Wh2  = Wh1 + GN;
  float* pO   = Wh2 + GN;
  float* pL   = pO + (size_t)4 * GN * GOC;
  int*   flag = (int*)(pL + 4 * GN);
  float* w2m  = (float*)(flag + 1);
  size_t need = (size_t)((char*)(w2m + 1) - (char*)d_ws);
  const int use_split = (ws_size >= need) ? 1 : 0;   // ws_size constant: same work every call
  if (!use_split) {                    // tight fallback layout without pO/pL
    flag = (int*)(Wh2 + GN);
    w2m  = (float*)(flag + 1);
  }

  const void* h = d_in[0]; const void* adj = d_in[1];
  const void* W = d_in[2]; const void* a = d_in[3];
  for (int i = 0; i < n_in; ++i) {
    long long s = in_sizes[i];
    if      (s == (long long)GN * GIC)  h   = d_in[i];
    else if (s == (long long)GN * GN)   adj = d_in[i];
    else if (s == (long long)GIC * GOC) W   = d_in[i];
    else if (s == 2LL * GOC)            a   = d_in[i];
  }

  const int n_out = GN * GOC;
  k_fill<<<(n_out + 255) / 256, 256, 0, stream>>>((uint16_t*)d_out, n_out);  // sentinel
  k_detect<<<1, 64, 0, stream>>>(W, flag);
  k_wh <<<GN / 8, 256, 0, stream>>>(h, W, a, WhF, Wh1, Wh2, flag);
  k_w2max<<<1, 256, 0, stream>>>(Wh2, w2m);
  if (use_split) {
    GraphAttentionLayer_P1_2834678415522_kernel<<<(GN / 32) * 4, 256, 0, stream>>>(
        (const int*)adj, WhF, Wh1, Wh2, w2m, pO, pL);
    k_comb<<<(GN * GOC) / 1024, 256, 0, stream>>>(pO, pL, d_out, flag);
  } else {
    k_gat1<<<GN / 16, 256, 0, stream>>>((const int*)adj, WhF, Wh1, Wh2, w2m,
                                        d_out, flag);
  }
}